// Round 5
// baseline (84.251 us; speedup 1.0000x reference)
//
#include <hip/hip_runtime.h>

#define NMAX 10
#define KPL  16          // hidden units per lane (1024 / 64)
#define L2E  1.4426950408889634f

typedef float f2 __attribute__((ext_vector_type(2)));

// ---------- DPP cross-lane sum (VALU pipe only) ----------
template<int CTRL, int RMASK, int BMASK>
__device__ __forceinline__ float dppmov(float v) {
    return __int_as_float(__builtin_amdgcn_update_dpp(
        0, __float_as_int(v), CTRL, RMASK, BMASK, true));
}
__device__ __forceinline__ float rdlane63(float v) {
    return __int_as_float(__builtin_amdgcn_readlane(__float_as_int(v), 63));
}

// two independent wave64 sums -> uniform scalars (2 chains for ILP)
__device__ __forceinline__ void wred2(float& a, float& b) {
    a += dppmov<0xB1, 0xf, 0xf>(a);  b += dppmov<0xB1, 0xf, 0xf>(b);  // quad xor1
    a += dppmov<0x4E, 0xf, 0xf>(a);  b += dppmov<0x4E, 0xf, 0xf>(b);  // quad xor2
    a += dppmov<0x141,0xf, 0xf>(a);  b += dppmov<0x141,0xf, 0xf>(b);  // half-row mirror
    a += dppmov<0x140,0xf, 0xf>(a);  b += dppmov<0x140,0xf, 0xf>(b);  // row mirror
    a += dppmov<0x142,0xa, 0xf>(a);  b += dppmov<0x142,0xa, 0xf>(b);  // row_bcast15
    a += dppmov<0x143,0xc, 0xf>(a);  b += dppmov<0x143,0xc, 0xf>(b);  // row_bcast31
    a = rdlane63(a);                 b = rdlane63(b);
}

// elu(p) = max(p,0) + exp(min(p,0)) - 1;  the "-1" is folded into the output
// bias:  bias' = b2 - sum_h(w2[h]).  All pairable ops packed (d-MLP in .x,
// v-MLP in .y) -> v_pk_fma_f32 / v_pk_min_f32 / v_pk_max_f32 full-rate fp32.
__device__ __forceinline__ void mlp_joint_pk(
    const f2 (&wy)[KPL], const f2 (&u)[KPL], const f2 (&w2)[KPL],
    float y, float dbias, float vbias, float& dout, float& vout)
{
    const f2 yv   = {y, y};
    const f2 zero = {0.f, 0.f};
    const f2 l2e  = {L2E, L2E};
    f2 acc0 = zero, acc1 = zero;
#pragma unroll
    for (int k = 0; k < KPL; k += 2) {
        f2 p0 = __builtin_elementwise_fma(wy[k],     yv, u[k]);
        f2 p1 = __builtin_elementwise_fma(wy[k + 1], yv, u[k + 1]);
        f2 q0 = __builtin_elementwise_min(p0, zero) * l2e;
        f2 q1 = __builtin_elementwise_min(p1, zero) * l2e;
        f2 e0, e1;
        e0.x = __builtin_amdgcn_exp2f(q0.x);  e0.y = __builtin_amdgcn_exp2f(q0.y);
        e1.x = __builtin_amdgcn_exp2f(q1.x);  e1.y = __builtin_amdgcn_exp2f(q1.y);
        f2 s0 = __builtin_elementwise_max(p0, zero) + e0;
        f2 s1 = __builtin_elementwise_max(p1, zero) + e1;
        acc0 = __builtin_elementwise_fma(w2[k],     s0, acc0);
        acc1 = __builtin_elementwise_fma(w2[k + 1], s1, acc1);
    }
    float a = acc0.x + acc1.x;
    float b = acc0.y + acc1.y;
    wred2(a, b);
    dout = a + dbias; vout = b + vbias;
}

__global__ __launch_bounds__(256) void rmodel_kernel(
    const float* __restrict__ X, const float* __restrict__ Y,
    const float* __restrict__ de_W1, const float* __restrict__ de_b1,
    const float* __restrict__ de_W2, const float* __restrict__ de_b2,
    const float* __restrict__ val_W1, const float* __restrict__ val_b1,
    const float* __restrict__ val_W2, const float* __restrict__ val_b2,
    float* __restrict__ out, int n)
{
    const int wid  = threadIdx.x >> 6;
    const int lane = threadIdx.x & 63;
    const int b    = blockIdx.x * 4 + wid;   // 4 consecutive samples per block
    if (b >= n) return;

    f2 wy[KPL], u[KPL], w2[KPL];             // .x = de-MLP, .y = val-MLP

    const float x  = X[b];
    const float y0 = Y[b];

    f2 sw = {0.f, 0.f};                      // sum of W2 (for the folded -1)
#pragma unroll
    for (int k = 0; k < KPL; ++k) {
        const int h = k * 64 + lane;
        float2 w1d = reinterpret_cast<const float2*>(de_W1)[h];
        float2 w1v = reinterpret_cast<const float2*>(val_W1)[h];
        wy[k] = (f2){w1d.y, w1v.y};
        u[k]  = (f2){fmaf(w1d.x, x, de_b1[h]), fmaf(w1v.x, x, val_b1[h])};
        w2[k] = (f2){de_W2[h], val_W2[h]};
        sw += w2[k];
    }
    float swd = sw.x, swv = sw.y;
    wred2(swd, swv);
    const float db2 = de_b2[0]  - swd;       // bias' = b2 - sum(w2)
    const float vb2 = val_b2[0] - swv;

    float* __restrict__ yout = out;                       // [NMAX+1][n]
    float* __restrict__ vout = out + (size_t)(NMAX + 1) * n;

    // ---- pipelined chain: each step jointly computes de(y_k) and val(y_k) ----
    float d, v;
    mlp_joint_pk(wy, u, w2, y0, db2, vb2, d, v);          // de(y0), v0
    if (lane == 0) { yout[b] = y0; vout[b] = v; }

    float y     = y0 + d;     // y1
    float vprev = v;          // v0
    float yfin  = y0, vfin = v;
    int   kend  = NMAX;       // last row actually computed

    for (int k = 1; k <= NMAX; ++k) {
        float dk, vk;
        mlp_joint_pk(wy, u, w2, y, db2, vb2, dk, vk);
        if (lane == 0) {
            yout[(size_t)k * n + b] = y;
            vout[(size_t)k * n + b] = vk;
        }
        yfin = y; vfin = vk;
        if (k >= 2 && vk >= vprev) { kend = k; break; }   // ref: break when i>0 && v_new >= v_prev
        vprev = vk;
        y += dk;               // speculative de-eval consumed only on continue
    }

    // ---- frozen rows: lanes store in parallel ----
    const int r = kend + 1 + lane;
    if (r <= NMAX) {
        yout[(size_t)r * n + b] = yfin;
        vout[(size_t)r * n + b] = vfin;
    }
}

extern "C" void kernel_launch(void* const* d_in, const int* in_sizes, int n_in,
                              void* d_out, int out_size, void* d_ws, size_t ws_size,
                              hipStream_t stream) {
    const float* X      = (const float*)d_in[0];
    const float* Y      = (const float*)d_in[1];
    const float* de_W1  = (const float*)d_in[2];
    const float* de_b1  = (const float*)d_in[3];
    const float* de_W2  = (const float*)d_in[4];
    const float* de_b2  = (const float*)d_in[5];
    const float* val_W1 = (const float*)d_in[6];
    const float* val_b1 = (const float*)d_in[7];
    const float* val_W2 = (const float*)d_in[8];
    const float* val_b2 = (const float*)d_in[9];
    float* out = (float*)d_out;

    const int n = in_sizes[0];               // 16384 samples
    dim3 block(256);                          // 4 waves/block, 1 wave = 1 sample
    dim3 grid((n + 3) / 4);
    hipLaunchKernelGGL(rmodel_kernel, grid, block, 0, stream,
                       X, Y, de_W1, de_b1, de_W2, de_b2,
                       val_W1, val_b1, val_W2, val_b2, out, n);
}

// Round 6
// 72.827 us; speedup vs baseline: 1.1569x; 1.1569x over previous
//
#include <hip/hip_runtime.h>

#define NMAX 10
#define KPL  16          // hidden units per lane (1024 / 64)
#define L2E  1.4426950408889634f
#define LN2  0.6931471805599453f

typedef float f2 __attribute__((ext_vector_type(2)));

// ---------- DPP cross-lane sum (VALU pipe only) ----------
template<int CTRL, int RMASK, int BMASK>
__device__ __forceinline__ float dppmov(float v) {
    return __int_as_float(__builtin_amdgcn_update_dpp(
        0, __float_as_int(v), CTRL, RMASK, BMASK, true));
}
__device__ __forceinline__ float rdlane63(float v) {
    return __int_as_float(__builtin_amdgcn_readlane(__float_as_int(v), 63));
}

// two independent wave64 sums -> uniform scalars (2 chains for ILP)
__device__ __forceinline__ void wred2(float& a, float& b) {
    a += dppmov<0xB1, 0xf, 0xf>(a);  b += dppmov<0xB1, 0xf, 0xf>(b);  // quad xor1
    a += dppmov<0x4E, 0xf, 0xf>(a);  b += dppmov<0x4E, 0xf, 0xf>(b);  // quad xor2
    a += dppmov<0x141,0xf, 0xf>(a);  b += dppmov<0x141,0xf, 0xf>(b);  // half-row mirror
    a += dppmov<0x140,0xf, 0xf>(a);  b += dppmov<0x140,0xf, 0xf>(b);  // row mirror
    a += dppmov<0x142,0xa, 0xf>(a);  b += dppmov<0x142,0xa, 0xf>(b);  // row_bcast15
    a += dppmov<0x143,0xc, 0xf>(a);  b += dppmov<0x143,0xc, 0xf>(b);  // row_bcast31
    a = rdlane63(a);                 b = rdlane63(b);
}

// Pre-scaled ELU-dot step.  With wy' = L2E*wy, u' = L2E*u, w2' = w2*ln2:
//   p' = p*L2E  (one pk_fma), e = exp2(p') = exp(p),
//   m  = med3(p', L2E*(e-1), 0) = L2E * elu(p)   [med3 commutes with >0 scale;
//        exp(p) >= 1+p guarantees branch ordering; inf/0 saturation exact]
//   acc += w2' * m  ==  w2 * elu(p).
__device__ __forceinline__ void mlp_joint(
    const f2 (&wy)[KPL], const f2 (&u)[KPL], const f2 (&w2)[KPL],
    float y, float dbias, float vbias, float& dout, float& vout)
{
    const f2 yv = {y, y};
    float ad0 = 0.f, ad1 = 0.f, av0 = 0.f, av1 = 0.f;
#pragma unroll
    for (int k = 0; k < KPL; k += 2) {
        f2 p0 = wy[k]     * yv + u[k];       // v_pk_fma_f32 (.x=de, .y=val)
        f2 p1 = wy[k + 1] * yv + u[k + 1];
        float e0x = __builtin_amdgcn_exp2f(p0.x);
        float e0y = __builtin_amdgcn_exp2f(p0.y);
        float e1x = __builtin_amdgcn_exp2f(p1.x);
        float e1y = __builtin_amdgcn_exp2f(p1.y);
        float m0x = __builtin_amdgcn_fmed3f(p0.x, fmaf(e0x, L2E, -L2E), 0.f);
        float m0y = __builtin_amdgcn_fmed3f(p0.y, fmaf(e0y, L2E, -L2E), 0.f);
        float m1x = __builtin_amdgcn_fmed3f(p1.x, fmaf(e1x, L2E, -L2E), 0.f);
        float m1y = __builtin_amdgcn_fmed3f(p1.y, fmaf(e1y, L2E, -L2E), 0.f);
        ad0 = fmaf(w2[k].x,     m0x, ad0);
        av0 = fmaf(w2[k].y,     m0y, av0);
        ad1 = fmaf(w2[k + 1].x, m1x, ad1);
        av1 = fmaf(w2[k + 1].y, m1y, av1);
    }
    float a = ad0 + ad1, b = av0 + av1;
    wred2(a, b);
    dout = a + dbias; vout = b + vbias;
}

__global__ __launch_bounds__(256) void rmodel_kernel(
    const float* __restrict__ X, const float* __restrict__ Y,
    const float* __restrict__ de_W1, const float* __restrict__ de_b1,
    const float* __restrict__ de_W2, const float* __restrict__ de_b2,
    const float* __restrict__ val_W1, const float* __restrict__ val_b1,
    const float* __restrict__ val_W2, const float* __restrict__ val_b2,
    float* __restrict__ out, int n)
{
    const int wid  = threadIdx.x >> 6;
    const int lane = threadIdx.x & 63;
    const int b    = blockIdx.x * 4 + wid;   // 4 consecutive samples per block
    if (b >= n) return;

    f2 wy[KPL], u[KPL], w2[KPL];             // .x = de-MLP, .y = val-MLP

    const float x  = X[b];
    const float y0 = Y[b];

#pragma unroll
    for (int k = 0; k < KPL; ++k) {
        const int h = k * 64 + lane;
        float2 w1d = reinterpret_cast<const float2*>(de_W1)[h];
        float2 w1v = reinterpret_cast<const float2*>(val_W1)[h];
        wy[k] = (f2){w1d.y * L2E, w1v.y * L2E};
        u[k]  = (f2){fmaf(w1d.x, x, de_b1[h]) * L2E,
                     fmaf(w1v.x, x, val_b1[h]) * L2E};
        w2[k] = (f2){de_W2[h] * LN2, val_W2[h] * LN2};
    }
    const float db2 = de_b2[0];
    const float vb2 = val_b2[0];

    float* __restrict__ yout = out;                       // [NMAX+1][n]
    float* __restrict__ vout = out + (size_t)(NMAX + 1) * n;

    // ---- pipelined chain: each step jointly computes de(y_k) and val(y_k) ----
    float d, v;
    mlp_joint(wy, u, w2, y0, db2, vb2, d, v);             // de(y0), v0
    if (lane == 0) { yout[b] = y0; vout[b] = v; }

    float y     = y0 + d;     // y1
    float vprev = v;          // v0
    float yfin  = y0, vfin = v;
    int   kend  = NMAX;       // last row actually computed

    float* yp = yout + b;
    float* vp = vout + b;
    for (int k = 1; k <= NMAX; ++k) {
        yp += n; vp += n;
        float dk, vk;
        mlp_joint(wy, u, w2, y, db2, vb2, dk, vk);
        if (lane == 0) { *yp = y; *vp = vk; }
        yfin = y; vfin = vk;
        if (k >= 2 && vk >= vprev) { kend = k; break; }   // ref: break when i>0 && v_new >= v_prev
        vprev = vk;
        y += dk;               // speculative de-eval consumed only on continue
    }

    // ---- frozen rows: lanes store in parallel ----
    const int r = kend + 1 + lane;
    if (r <= NMAX) {
        yout[(size_t)r * n + b] = yfin;
        vout[(size_t)r * n + b] = vfin;
    }
}

extern "C" void kernel_launch(void* const* d_in, const int* in_sizes, int n_in,
                              void* d_out, int out_size, void* d_ws, size_t ws_size,
                              hipStream_t stream) {
    const float* X      = (const float*)d_in[0];
    const float* Y      = (const float*)d_in[1];
    const float* de_W1  = (const float*)d_in[2];
    const float* de_b1  = (const float*)d_in[3];
    const float* de_W2  = (const float*)d_in[4];
    const float* de_b2  = (const float*)d_in[5];
    const float* val_W1 = (const float*)d_in[6];
    const float* val_b1 = (const float*)d_in[7];
    const float* val_W2 = (const float*)d_in[8];
    const float* val_b2 = (const float*)d_in[9];
    float* out = (float*)d_out;

    const int n = in_sizes[0];               // 16384 samples
    dim3 block(256);                          // 4 waves/block, 1 wave = 1 sample
    dim3 grid((n + 3) / 4);
    hipLaunchKernelGGL(rmodel_kernel, grid, block, 0, stream,
                       X, Y, de_W1, de_b1, de_W2, de_b2,
                       val_W1, val_b1, val_W2, val_b2, out, n);
}